// Round 1
// baseline (1103.547 us; speedup 1.0000x reference)
//
#include <hip/hip_runtime.h>
#include <cstdint>
#include <cstddef>

typedef _Float16 f16;
typedef _Float16 f16x8 __attribute__((ext_vector_type(8)));
typedef _Float16 f16x4 __attribute__((ext_vector_type(4)));
typedef float    f32x4 __attribute__((ext_vector_type(4)));

#define BM 128
#define BN 128
#define BK 32
#define BKP 40   // +8 halfs (16B) pad: breaks 64B-row bank aliasing, keeps 16B alignment

// ---------------------------------------------------------------------------
// fp32 -> fp16 conversion (vectorized, n % 1024 == 0)
// ---------------------------------------------------------------------------
__global__ __launch_bounds__(256) void cvt_f32_f16(const float* __restrict__ in,
                                                   f16* __restrict__ out, int n) {
  int i = (blockIdx.x * 256 + threadIdx.x) * 4;
  if (i < n) {
    float4 v = *(const float4*)(in + i);
    f16x4 h; h[0] = (f16)v.x; h[1] = (f16)v.y; h[2] = (f16)v.z; h[3] = (f16)v.w;
    *(f16x4*)(out + i) = h;
  }
}

// ---------------------------------------------------------------------------
// 64x64-tiled fp16 transpose: in [R][C] -> out [C][R]
// ---------------------------------------------------------------------------
__global__ __launch_bounds__(256) void transpose_f16(const f16* __restrict__ in,
                                                     f16* __restrict__ out,
                                                     int R, int C) {
  __shared__ f16 tile[64][65];
  const int r0 = blockIdx.y * 64, c0 = blockIdx.x * 64;
  const int t = threadIdx.x;
#pragma unroll
  for (int p = 0; p < 2; p++) {
    int s = t + p * 256;           // 512 f16x8 slots
    int r = s >> 3, q = s & 7;
    f16x8 v = *(const f16x8*)(in + (size_t)(r0 + r) * C + c0 + q * 8);
#pragma unroll
    for (int e = 0; e < 8; e++) tile[r][q * 8 + e] = v[e];
  }
  __syncthreads();
#pragma unroll
  for (int p = 0; p < 2; p++) {
    int s = t + p * 256;
    int r = s >> 3, q = s & 7;     // r = output-row index (c-dim), q*8+e = r-dim
    f16x8 v;
#pragma unroll
    for (int e = 0; e < 8; e++) v[e] = tile[q * 8 + e][r];
    *(f16x8*)(out + (size_t)(c0 + r) * R + r0 + q * 8) = v;
  }
}

// ---------------------------------------------------------------------------
// BT GEMM: C[m][n] = sum_k A[m][k] * B[n][k]   (both k-inner row-major)
// MODE 0: out fp16 = acc + bias[n]                       (QKV)
// MODE 1: out fp16 = acc - rowmax(64-col wave tile); stats[row][2*bx+wc]=max  (S)
// MODE 2: out fp16 = acc                                 (ctx; 1/l pre-folded)
// MODE 3: out fp32 = acc + bias[n] + resid[m][n]         (fc0 + residual)
// MODE 4: out fp32 = acc + bias[n]                       (fc1)
// AF32: A is fp32, converted to fp16 during LDS staging.
// ---------------------------------------------------------------------------
template <int MODE, bool AF32>
__global__ __launch_bounds__(256) void gemm_bt(
    const void* __restrict__ Av, const f16* __restrict__ B,
    int M, int N, int K, int lda, int ldb,
    const float* __restrict__ bias,
    f16* __restrict__ outH, int ldo,
    float* __restrict__ stats, int sld,
    const float* __restrict__ resid, int ldr,
    float* __restrict__ outF, int ldof) {
  __shared__ f16 lA[BM * BKP];
  __shared__ f16 lB[BN * BKP];
  const int t = threadIdx.x;
  const int bn = blockIdx.x, bm = blockIdx.y;
  const int m0 = bm * BM, n0 = bn * BN;
  const int wave = t >> 6, lane = t & 63;
  const int wr = wave >> 1, wc = wave & 1;
  const int quad = lane >> 4, l16 = lane & 15;

  f32x4 acc[4][4];
#pragma unroll
  for (int i = 0; i < 4; i++)
#pragma unroll
    for (int j = 0; j < 4; j++)
#pragma unroll
      for (int e = 0; e < 4; e++) acc[i][j][e] = 0.0f;

  const int nk = K / BK;
  for (int kt = 0; kt < nk; ++kt) {
    const int k0 = kt * BK;
    // ---- stage A tile (128 x 32) ----
    if constexpr (AF32) {
      const float* A = (const float*)Av;
#pragma unroll
      for (int p = 0; p < 4; p++) {
        int s = t + p * 256;          // 1024 float4 slots
        int row = s >> 3, q4 = s & 7;
        float4 v = *(const float4*)(A + (size_t)(m0 + row) * lda + k0 + q4 * 4);
        f16x4 h; h[0] = (f16)v.x; h[1] = (f16)v.y; h[2] = (f16)v.z; h[3] = (f16)v.w;
        *(f16x4*)(&lA[row * BKP + q4 * 4]) = h;
      }
    } else {
      const f16* A = (const f16*)Av;
#pragma unroll
      for (int p = 0; p < 2; p++) {
        int s = t + p * 256;          // 512 f16x8 slots
        int row = s >> 2, q = s & 3;
        f16x8 v = *(const f16x8*)(A + (size_t)(m0 + row) * lda + k0 + q * 8);
        *(f16x8*)(&lA[row * BKP + q * 8]) = v;
      }
    }
    // ---- stage B tile (128 x 32) ----
#pragma unroll
    for (int p = 0; p < 2; p++) {
      int s = t + p * 256;
      int row = s >> 2, q = s & 3;
      f16x8 v = *(const f16x8*)(B + (size_t)(n0 + row) * ldb + k0 + q * 8);
      *(f16x8*)(&lB[row * BKP + q * 8]) = v;
    }
    __syncthreads();
    // ---- fragments + MFMA ----
    f16x8 af[4], bf[4];
#pragma unroll
    for (int i = 0; i < 4; i++)
      af[i] = *(f16x8*)(&lA[(wr * 64 + i * 16 + l16) * BKP + quad * 8]);
#pragma unroll
    for (int j = 0; j < 4; j++)
      bf[j] = *(f16x8*)(&lB[(wc * 64 + j * 16 + l16) * BKP + quad * 8]);
#pragma unroll
    for (int i = 0; i < 4; i++)
#pragma unroll
      for (int j = 0; j < 4; j++)
        acc[i][j] = __builtin_amdgcn_mfma_f32_16x16x32_f16(af[i], bf[j], acc[i][j], 0, 0, 0);
    __syncthreads();
  }

  // ---- epilogue ----
  const int mrow = m0 + wr * 64;
  const int ncol = n0 + wc * 64;
  float bv[4];
  if constexpr (MODE == 0 || MODE == 3 || MODE == 4) {
#pragma unroll
    for (int j = 0; j < 4; j++) bv[j] = bias[ncol + j * 16 + l16];
  }
#pragma unroll
  for (int fi = 0; fi < 4; fi++) {
#pragma unroll
    for (int i = 0; i < 4; i++) {
      const int gr = mrow + fi * 16 + quad * 4 + i;
      if constexpr (MODE == 1) {
        float mx = acc[fi][0][i];
        mx = fmaxf(mx, acc[fi][1][i]);
        mx = fmaxf(mx, acc[fi][2][i]);
        mx = fmaxf(mx, acc[fi][3][i]);
        mx = fmaxf(mx, __shfl_xor(mx, 1));
        mx = fmaxf(mx, __shfl_xor(mx, 2));
        mx = fmaxf(mx, __shfl_xor(mx, 4));
        mx = fmaxf(mx, __shfl_xor(mx, 8));
        if (l16 == 0) stats[(size_t)gr * sld + (blockIdx.x * 2 + wc)] = mx;
#pragma unroll
        for (int fj = 0; fj < 4; fj++) {
          const int gc = ncol + fj * 16 + l16;
          outH[(size_t)gr * ldo + gc] = (f16)(acc[fi][fj][i] - mx);
        }
      } else {
#pragma unroll
        for (int fj = 0; fj < 4; fj++) {
          const int gc = ncol + fj * 16 + l16;
          float v = acc[fi][fj][i];
          if constexpr (MODE == 0) outH[(size_t)gr * ldo + gc] = (f16)(v + bv[fj]);
          if constexpr (MODE == 2) outH[(size_t)gr * ldo + gc] = (f16)v;
          if constexpr (MODE == 3)
            outF[(size_t)gr * ldof + gc] = v + bv[fj] + resid[(size_t)gr * ldr + gc];
          if constexpr (MODE == 4) outF[(size_t)gr * ldof + gc] = v + bv[fj];
        }
      }
    }
  }
}

// ---------------------------------------------------------------------------
// Row softmax, in place on S (stored as s - tile_max, fp16), folds 1/l.
// One block per row; 256 threads x 32 cols = 8192.
// ---------------------------------------------------------------------------
__global__ __launch_bounds__(256) void softmax_row(f16* __restrict__ S,
                                                   const float* __restrict__ stats,
                                                   int N, int sld) {
  const int row = blockIdx.x;
  const int t = threadIdx.x;
  __shared__ float sm[128];
  __shared__ float red[4];
  if (t < 128) sm[t] = stats[(size_t)row * sld + t];
  __syncthreads();
  float m = -1e30f;
#pragma unroll 16
  for (int i = 0; i < 128; i++) m = fmaxf(m, sm[i]);

  f16* rp = S + (size_t)row * N + t * 32;
  const float d = sm[t >> 1] - m;   // tile index of cols [t*32, t*32+31] is t/2
  float ev[32];
  float sum = 0.0f;
#pragma unroll
  for (int v8 = 0; v8 < 4; v8++) {
    f16x8 v = *(f16x8*)(rp + v8 * 8);
#pragma unroll
    for (int e = 0; e < 8; e++) {
      float x = (float)v[e] + d;
      float ex = __expf(x);
      ev[v8 * 8 + e] = ex;
      sum += ex;
    }
  }
#pragma unroll
  for (int off = 32; off > 0; off >>= 1) sum += __shfl_down(sum, off);
  if ((t & 63) == 0) red[t >> 6] = sum;
  __syncthreads();
  const float rl = 1.0f / (red[0] + red[1] + red[2] + red[3]);
#pragma unroll
  for (int v8 = 0; v8 < 4; v8++) {
    f16x8 v;
#pragma unroll
    for (int e = 0; e < 8; e++) v[e] = (f16)(ev[v8 * 8 + e] * rl);
    *(f16x8*)(rp + v8 * 8) = v;
  }
}

// ---------------------------------------------------------------------------
extern "C" void kernel_launch(void* const* d_in, const int* in_sizes, int n_in,
                              void* d_out, int out_size, void* d_ws, size_t ws_size,
                              hipStream_t stream) {
  const float* O0   = (const float*)d_in[0];
  const float* Ww   = (const float*)d_in[1];
  const float* Wb   = (const float*)d_in[2];
  const float* Uw   = (const float*)d_in[3];
  const float* Ub   = (const float*)d_in[4];
  const float* Hw   = (const float*)d_in[5];
  const float* Hb   = (const float*)d_in[6];
  const float* fc0w = (const float*)d_in[7];
  const float* fc0b = (const float*)d_in[8];
  const float* fc1w = (const float*)d_in[9];
  const float* fc1b = (const float*)d_in[10];

  const int N = 8192, D = 2048, DH = 1024, DO = 1024;

  // workspace layout (~175 MB)
  char* w = (char*)d_ws;
  f16* Wwh   = (f16*)w; w += (size_t)DH * D * 2;      // 4 MB
  f16* Uwh   = (f16*)w; w += (size_t)DH * D * 2;      // 4 MB
  f16* Hwh   = (f16*)w; w += (size_t)DH * D * 2;      // 4 MB
  f16* fc0wh = (f16*)w; w += (size_t)D * DH * 2;      // 4 MB
  f16* fc1wh = (f16*)w; w += (size_t)DO * D * 2;      // 4 MB
  f16* ctxh  = (f16*)w; w += (size_t)N * DH * 2;      // 16 MB
  float* stats = (float*)w; w += (size_t)N * 128 * 4; // 4 MB
  f16* Sb    = (f16*)w;                               // 128 MiB (S, then P~ in place)

  // q,k,vT live in d_out until fc0 overwrites it (all dead by then)
  f16* oh = (f16*)d_out;
  f16* qh = oh;                                       // [N][DH]
  f16* kh = oh + (size_t)N * DH;                      // [N][DH]
  f16* vT = oh + (size_t)2 * N * DH;                  // [DH][N]
  f16* vtmp = Sb;                                     // v row-major, temp (pre-S)

  // 1) convert weights to fp16
  {
    int n = DH * D;  // 2M, same for all five
    int grid = n / 1024;
    cvt_f32_f16<<<grid, 256, 0, stream>>>(Ww, Wwh, n);
    cvt_f32_f16<<<grid, 256, 0, stream>>>(Uw, Uwh, n);
    cvt_f32_f16<<<grid, 256, 0, stream>>>(Hw, Hwh, n);
    cvt_f32_f16<<<grid, 256, 0, stream>>>(fc0w, fc0wh, n);
    cvt_f32_f16<<<grid, 256, 0, stream>>>(fc1w, fc1wh, n);
  }

  // 2) QKV GEMMs: A = O0 (fp32, cvt in staging), B = W* [DH][D]
  {
    dim3 g(DH / BN, N / BM);
    gemm_bt<0, true><<<g, 256, 0, stream>>>(O0, Wwh, N, DH, D, D, D, Wb,
                                            qh, DH, nullptr, 0, nullptr, 0, nullptr, 0);
    gemm_bt<0, true><<<g, 256, 0, stream>>>(O0, Uwh, N, DH, D, D, D, Ub,
                                            kh, DH, nullptr, 0, nullptr, 0, nullptr, 0);
    gemm_bt<0, true><<<g, 256, 0, stream>>>(O0, Hwh, N, DH, D, D, D, Hb,
                                            vtmp, DH, nullptr, 0, nullptr, 0, nullptr, 0);
  }

  // 3) transpose v: [N][DH] -> [DH][N]
  transpose_f16<<<dim3(DH / 64, N / 64), 256, 0, stream>>>(vtmp, vT, N, DH);

  // 4) S = q @ k^T, stored fp16 as (s - tile_max), stats = per-64-col-tile row max
  gemm_bt<1, false><<<dim3(N / BN, N / BM), 256, 0, stream>>>(
      qh, kh, N, N, DH, DH, DH, nullptr, Sb, N, stats, 128, nullptr, 0, nullptr, 0);

  // 5) softmax in place (folds 1/l)
  softmax_row<<<N, 256, 0, stream>>>(Sb, stats, N, 128);

  // 6) ctx = P~ @ v  (B = vT [DH][N])
  gemm_bt<2, false><<<dim3(DH / BN, N / BM), 256, 0, stream>>>(
      Sb, vT, N, DH, N, N, N, nullptr, ctxh, DH, nullptr, 0, nullptr, 0, nullptr, 0);

  // 7) O1 = O0 + ctx @ fc0w^T + fc0b  -> d_out fp32 (overwrites q/k/vT region: all dead)
  gemm_bt<3, false><<<dim3(D / BN, N / BM), 256, 0, stream>>>(
      ctxh, fc0wh, N, D, DH, DH, DH, fc0b, nullptr, 0, nullptr, 0,
      O0, D, (float*)d_out, D);

  // 8) O2 = O1 @ fc1w^T + fc1b  (A = O1 fp32 from d_out, cvt in staging)
  gemm_bt<4, true><<<dim3(DO / BN, N / BM), 256, 0, stream>>>(
      (const float*)d_out, fc1wh, N, DO, D, D, D, fc1b, nullptr, 0, nullptr, 0,
      nullptr, 0, (float*)d_out + (size_t)N * D, DO);
}

// Round 2
// 888.859 us; speedup vs baseline: 1.2415x; 1.2415x over previous
//
#include <hip/hip_runtime.h>
#include <cstdint>
#include <cstddef>

typedef _Float16 f16;
typedef _Float16 f16x8 __attribute__((ext_vector_type(8)));
typedef _Float16 f16x4 __attribute__((ext_vector_type(4)));
typedef float    f32x4 __attribute__((ext_vector_type(4)));

#define BM 128
#define BN 128
#define BK 64
// LDS tile: 128 rows x 64 halfs (128 B rows = 32 banks exactly, no pad —
// required by global_load_lds's wave-uniform-base+lane*16 dest).
// Within a row, 16B slot p holds global k-chunk (p ^ (row&7)): fragment
// ds_read_b128 lands 2-way per bank (free, m136) instead of 8/16-way.

// ---------------------------------------------------------------------------
__global__ __launch_bounds__(256) void cvt_f32_f16(const float* __restrict__ in,
                                                   f16* __restrict__ out, int n) {
  int i = (blockIdx.x * 256 + threadIdx.x) * 4;
  if (i < n) {
    float4 v = *(const float4*)(in + i);
    f16x4 h; h[0] = (f16)v.x; h[1] = (f16)v.y; h[2] = (f16)v.z; h[3] = (f16)v.w;
    *(f16x4*)(out + i) = h;
  }
}

// ---------------------------------------------------------------------------
__global__ __launch_bounds__(256) void transpose_f16(const f16* __restrict__ in,
                                                     f16* __restrict__ out,
                                                     int R, int C) {
  __shared__ f16 tile[64][65];
  const int r0 = blockIdx.y * 64, c0 = blockIdx.x * 64;
  const int t = threadIdx.x;
#pragma unroll
  for (int p = 0; p < 2; p++) {
    int s = t + p * 256;
    int r = s >> 3, q = s & 7;
    f16x8 v = *(const f16x8*)(in + (size_t)(r0 + r) * C + c0 + q * 8);
#pragma unroll
    for (int e = 0; e < 8; e++) tile[r][q * 8 + e] = v[e];
  }
  __syncthreads();
#pragma unroll
  for (int p = 0; p < 2; p++) {
    int s = t + p * 256;
    int r = s >> 3, q = s & 7;
    f16x8 v;
#pragma unroll
    for (int e = 0; e < 8; e++) v[e] = tile[q * 8 + e][r];
    *(f16x8*)(out + (size_t)(c0 + r) * R + r0 + q * 8) = v;
  }
}

// ---------------------------------------------------------------------------
// BT GEMM, all-fp16 inputs: C[m][n] = sum_k A[m][k]*B[n][k]
// MODE 0: outH fp16 = acc + bias[n]                    (QKV)
// MODE 1: outH fp16 = acc - wavetile_rowmax; stats[row][2*bx+wc] = max   (S)
// MODE 2: outH fp16 = acc                              (ctx)
// MODE 3: outF fp32 = acc + bias + resid; outH fp16 = same  (fc0 + residual)
// MODE 4: outF fp32 = acc + bias                       (fc1)
// ---------------------------------------------------------------------------
template <int MODE>
__global__ __launch_bounds__(256) void gemm_bt(
    const f16* __restrict__ A, const f16* __restrict__ B,
    int M, int N, int K, int lda, int ldb,
    const float* __restrict__ bias,
    f16* __restrict__ outH, int ldo,
    float* __restrict__ stats, int sld,
    const float* __restrict__ resid, int ldr,
    float* __restrict__ outF, int ldof) {
  __shared__ f16 lA[BM * BK];
  __shared__ f16 lB[BN * BK];
  const int t = threadIdx.x;
  const int bn = blockIdx.x, bm = blockIdx.y;
  const int m0 = bm * BM, n0 = bn * BN;
  const int wave = t >> 6, lane = t & 63;
  const int wr = wave >> 1, wc = wave & 1;
  const int quad = lane >> 4, l16 = lane & 15;

  // staging geometry: chunk = 8 rows x 128 B = 1024 B; lane covers
  // (row = lane>>3, slot = lane&7); global k-chunk is XOR-swizzled.
  const int rc = lane >> 3;
  const int kcs = (lane & 7) ^ rc;
  const f16* gA = A + (size_t)(m0 + rc) * lda + kcs * 8;
  const f16* gB = B + (size_t)(n0 + rc) * ldb + kcs * 8;

  f32x4 acc[4][4];
#pragma unroll
  for (int i = 0; i < 4; i++)
#pragma unroll
    for (int j = 0; j < 4; j++)
#pragma unroll
      for (int e = 0; e < 4; e++) acc[i][j][e] = 0.0f;

  const int nk = K / BK;
  for (int kt = 0; kt < nk; ++kt) {
#pragma unroll
    for (int j = 0; j < 4; j++) {
      const int c = wave * 4 + j;  // wave-uniform chunk id
      __builtin_amdgcn_global_load_lds(
          (const __attribute__((address_space(1))) void*)(gA + (size_t)c * 8 * lda),
          (__attribute__((address_space(3))) void*)(lA + c * 512), 16, 0, 0);
    }
#pragma unroll
    for (int j = 0; j < 4; j++) {
      const int c = wave * 4 + j;
      __builtin_amdgcn_global_load_lds(
          (const __attribute__((address_space(1))) void*)(gB + (size_t)c * 8 * ldb),
          (__attribute__((address_space(3))) void*)(lB + c * 512), 16, 0, 0);
    }
    gA += BK; gB += BK;
    __syncthreads();

    f16x8 af[2][4], bf[2][4];
#pragma unroll
    for (int h = 0; h < 2; h++) {
      const int p = ((h * 4 + quad) ^ (l16 & 7)) * 8;
#pragma unroll
      for (int i = 0; i < 4; i++)
        af[h][i] = *(const f16x8*)(lA + (wr * 64 + i * 16 + l16) * 64 + p);
#pragma unroll
      for (int j = 0; j < 4; j++)
        bf[h][j] = *(const f16x8*)(lB + (wc * 64 + j * 16 + l16) * 64 + p);
    }
#pragma unroll
    for (int h = 0; h < 2; h++)
#pragma unroll
      for (int i = 0; i < 4; i++)
#pragma unroll
        for (int j = 0; j < 4; j++)
          acc[i][j] = __builtin_amdgcn_mfma_f32_16x16x32_f16(af[h][i], bf[h][j],
                                                             acc[i][j], 0, 0, 0);
    __syncthreads();
  }

  // ---- epilogue ----
  const int mrow = m0 + wr * 64;
  const int ncol = n0 + wc * 64;
  float bv[4];
  if constexpr (MODE == 0 || MODE == 3 || MODE == 4) {
#pragma unroll
    for (int j = 0; j < 4; j++) bv[j] = bias[ncol + j * 16 + l16];
  }
#pragma unroll
  for (int fi = 0; fi < 4; fi++) {
#pragma unroll
    for (int i = 0; i < 4; i++) {
      const int gr = mrow + fi * 16 + quad * 4 + i;
      if constexpr (MODE == 1) {
        float mx = acc[fi][0][i];
        mx = fmaxf(mx, acc[fi][1][i]);
        mx = fmaxf(mx, acc[fi][2][i]);
        mx = fmaxf(mx, acc[fi][3][i]);
        mx = fmaxf(mx, __shfl_xor(mx, 1));
        mx = fmaxf(mx, __shfl_xor(mx, 2));
        mx = fmaxf(mx, __shfl_xor(mx, 4));
        mx = fmaxf(mx, __shfl_xor(mx, 8));
        if (l16 == 0) stats[(size_t)gr * sld + (blockIdx.x * 2 + wc)] = mx;
#pragma unroll
        for (int fj = 0; fj < 4; fj++) {
          const int gc = ncol + fj * 16 + l16;
          outH[(size_t)gr * ldo + gc] = (f16)(acc[fi][fj][i] - mx);
        }
      } else {
#pragma unroll
        for (int fj = 0; fj < 4; fj++) {
          const int gc = ncol + fj * 16 + l16;
          float v = acc[fi][fj][i];
          if constexpr (MODE == 0) outH[(size_t)gr * ldo + gc] = (f16)(v + bv[fj]);
          if constexpr (MODE == 2) outH[(size_t)gr * ldo + gc] = (f16)v;
          if constexpr (MODE == 3) {
            float o = v + bv[fj] + resid[(size_t)gr * ldr + gc];
            outF[(size_t)gr * ldof + gc] = o;
            outH[(size_t)gr * ldo + gc] = (f16)o;
          }
          if constexpr (MODE == 4) outF[(size_t)gr * ldof + gc] = v + bv[fj];
        }
      }
    }
  }
}

// ---------------------------------------------------------------------------
__global__ __launch_bounds__(256) void softmax_row(f16* __restrict__ S,
                                                   const float* __restrict__ stats,
                                                   int N, int sld) {
  const int row = blockIdx.x;
  const int t = threadIdx.x;
  __shared__ float sm[128];
  __shared__ float red[4];
  if (t < 128) sm[t] = stats[(size_t)row * sld + t];
  __syncthreads();
  float m = -1e30f;
#pragma unroll 16
  for (int i = 0; i < 128; i++) m = fmaxf(m, sm[i]);

  f16* rp = S + (size_t)row * N + t * 32;
  const float d = sm[t >> 1] - m;
  float ev[32];
  float sum = 0.0f;
#pragma unroll
  for (int v8 = 0; v8 < 4; v8++) {
    f16x8 v = *(f16x8*)(rp + v8 * 8);
#pragma unroll
    for (int e = 0; e < 8; e++) {
      float x = (float)v[e] + d;
      float ex = __expf(x);
      ev[v8 * 8 + e] = ex;
      sum += ex;
    }
  }
#pragma unroll
  for (int off = 32; off > 0; off >>= 1) sum += __shfl_down(sum, off);
  if ((t & 63) == 0) red[t >> 6] = sum;
  __syncthreads();
  const float rl = 1.0f / (red[0] + red[1] + red[2] + red[3]);
#pragma unroll
  for (int v8 = 0; v8 < 4; v8++) {
    f16x8 v;
#pragma unroll
    for (int e = 0; e < 8; e++) v[e] = (f16)(ev[v8 * 8 + e] * rl);
    *(f16x8*)(rp + v8 * 8) = v;
  }
}

// ---------------------------------------------------------------------------
extern "C" void kernel_launch(void* const* d_in, const int* in_sizes, int n_in,
                              void* d_out, int out_size, void* d_ws, size_t ws_size,
                              hipStream_t stream) {
  const float* O0   = (const float*)d_in[0];
  const float* Ww   = (const float*)d_in[1];
  const float* Wb   = (const float*)d_in[2];
  const float* Uw   = (const float*)d_in[3];
  const float* Ub   = (const float*)d_in[4];
  const float* Hw   = (const float*)d_in[5];
  const float* Hb   = (const float*)d_in[6];
  const float* fc0w = (const float*)d_in[7];
  const float* fc0b = (const float*)d_in[8];
  const float* fc1w = (const float*)d_in[9];
  const float* fc1b = (const float*)d_in[10];

  const int N = 8192, D = 2048, DH = 1024, DO = 1024;

  // workspace (~168 MB, same budget as round 1)
  char* w = (char*)d_ws;
  f16* Wwh   = (f16*)w; w += (size_t)DH * D * 2;
  f16* Uwh   = (f16*)w; w += (size_t)DH * D * 2;
  f16* Hwh   = (f16*)w; w += (size_t)DH * D * 2;
  f16* fc0wh = (f16*)w; w += (size_t)D * DH * 2;
  f16* fc1wh = (f16*)w; w += (size_t)DO * D * 2;
  f16* ctxh  = (f16*)w; w += (size_t)N * DH * 2;
  float* stats = (float*)w; w += (size_t)N * 128 * 4;
  f16* Sb    = (f16*)w;                 // 128 MiB: S -> P~ -> (dead) -> O1h

  // d_out scratch (96 MB total): q,k,vT (48 MB) + O0h (32 MB); all dead
  // before fc0 writes O1 fp32 at d_out[0..64MB].
  f16* oh  = (f16*)d_out;
  f16* qh  = oh;
  f16* kh  = oh + (size_t)N * DH;
  f16* vT  = oh + (size_t)2 * N * DH;
  f16* O0h = oh + (size_t)3 * N * DH;
  f16* vtmp = Sb;            // v row-major temp (pre-S)
  f16* O1h  = Sb;            // after ctx, Sb is dead -> holds O1 fp16

  // 1) fp32 -> fp16 conversions
  {
    int n = DH * D;
    int grid = n / 1024;
    cvt_f32_f16<<<grid, 256, 0, stream>>>(Ww, Wwh, n);
    cvt_f32_f16<<<grid, 256, 0, stream>>>(Uw, Uwh, n);
    cvt_f32_f16<<<grid, 256, 0, stream>>>(Hw, Hwh, n);
    cvt_f32_f16<<<grid, 256, 0, stream>>>(fc0w, fc0wh, n);
    cvt_f32_f16<<<grid, 256, 0, stream>>>(fc1w, fc1wh, n);
    int n0 = N * D;
    cvt_f32_f16<<<n0 / 1024, 256, 0, stream>>>(O0, O0h, n0);
  }

  // 2) QKV
  {
    dim3 g(DH / BN, N / BM);
    gemm_bt<0><<<g, 256, 0, stream>>>(O0h, Wwh, N, DH, D, D, D, Wb,
                                      qh, DH, nullptr, 0, nullptr, 0, nullptr, 0);
    gemm_bt<0><<<g, 256, 0, stream>>>(O0h, Uwh, N, DH, D, D, D, Ub,
                                      kh, DH, nullptr, 0, nullptr, 0, nullptr, 0);
    gemm_bt<0><<<g, 256, 0, stream>>>(O0h, Hwh, N, DH, D, D, D, Hb,
                                      vtmp, DH, nullptr, 0, nullptr, 0, nullptr, 0);
  }

  // 3) v -> vT
  transpose_f16<<<dim3(DH / 64, N / 64), 256, 0, stream>>>(vtmp, vT, N, DH);

  // 4) S = q k^T (stored as s - tilemax) + per-tile row maxes
  gemm_bt<1><<<dim3(N / BN, N / BM), 256, 0, stream>>>(
      qh, kh, N, N, DH, DH, DH, nullptr, Sb, N, stats, 128, nullptr, 0, nullptr, 0);

  // 5) softmax in place (folds 1/l)
  softmax_row<<<N, 256, 0, stream>>>(Sb, stats, N, 128);

  // 6) ctx = P~ @ v
  gemm_bt<2><<<dim3(DH / BN, N / BM), 256, 0, stream>>>(
      Sb, vT, N, DH, N, N, N, nullptr, ctxh, DH, nullptr, 0, nullptr, 0, nullptr, 0);

  // 7) O1 = O0 + ctx @ fc0w^T + fc0b -> fp32 d_out, fp16 O1h
  gemm_bt<3><<<dim3(D / BN, N / BM), 256, 0, stream>>>(
      ctxh, fc0wh, N, D, DH, DH, DH, fc0b, O1h, D, nullptr, 0,
      O0, D, (float*)d_out, D);

  // 8) O2 = O1 @ fc1w^T + fc1b
  gemm_bt<4><<<dim3(DO / BN, N / BM), 256, 0, stream>>>(
      O1h, fc1wh, N, DO, D, D, D, fc1b, nullptr, 0, nullptr, 0,
      nullptr, 0, (float*)d_out + (size_t)N * D, DO);
}

// Round 3
// 862.917 us; speedup vs baseline: 1.2789x; 1.0301x over previous
//
#include <hip/hip_runtime.h>
#include <cstdint>
#include <cstddef>

typedef _Float16 f16;
typedef _Float16 f16x8 __attribute__((ext_vector_type(8)));
typedef _Float16 f16x4 __attribute__((ext_vector_type(4)));
typedef float    f32x4 __attribute__((ext_vector_type(4)));

#define BM 128
#define BN 128
#define BK 64
// LDS tile: 128 rows x 64 halfs, no pad (global_load_lds needs lane-contiguous
// dest). 16B slot p of row r holds global k-chunk (p ^ (r&7)); fragment
// ds_read_b128 then lands 2-way per bank (free, m136). Verified R2: 0 conflicts.

// ---------------------------------------------------------------------------
__global__ __launch_bounds__(256) void cvt_f32_f16(const float* __restrict__ in,
                                                   f16* __restrict__ out, int n) {
  int i = (blockIdx.x * 256 + threadIdx.x) * 4;
  if (i < n) {
    float4 v = *(const float4*)(in + i);
    f16x4 h; h[0] = (f16)v.x; h[1] = (f16)v.y; h[2] = (f16)v.z; h[3] = (f16)v.w;
    *(f16x4*)(out + i) = h;
  }
}

// ---------------------------------------------------------------------------
// in [R][ldi] (reading a C-col slice) -> out [C][R]
__global__ __launch_bounds__(256) void transpose_f16(const f16* __restrict__ in,
                                                     int ldi,
                                                     f16* __restrict__ out,
                                                     int R, int C) {
  __shared__ f16 tile[64][65];
  const int r0 = blockIdx.y * 64, c0 = blockIdx.x * 64;
  const int t = threadIdx.x;
#pragma unroll
  for (int p = 0; p < 2; p++) {
    int s = t + p * 256;
    int r = s >> 3, q = s & 7;
    f16x8 v = *(const f16x8*)(in + (size_t)(r0 + r) * ldi + c0 + q * 8);
#pragma unroll
    for (int e = 0; e < 8; e++) tile[r][q * 8 + e] = v[e];
  }
  __syncthreads();
#pragma unroll
  for (int p = 0; p < 2; p++) {
    int s = t + p * 256;
    int r = s >> 3, q = s & 7;
    f16x8 v;
#pragma unroll
    for (int e = 0; e < 8; e++) v[e] = tile[q * 8 + e][r];
    *(f16x8*)(out + (size_t)(c0 + r) * R + r0 + q * 8) = v;
  }
}

// ---------------------------------------------------------------------------
// BT GEMM, fp16: C[m][n] = sum_k A[m][k]*B[n][k]
// MODE 0: outH = acc + bias[n]                         (QKV merged)
// MODE 1: outH = acc - wavetile_rowmax; stats[r][2bx+wc]=max   (S)
// MODE 2: outH = acc                                   (ctx)
// MODE 3: outF = acc + bias + resid (fp32); outH = same (fp16)  (fc0)
// MODE 4: outF = acc + bias (fp32)                     (fc1)
// ---------------------------------------------------------------------------
template <int MODE>
__global__ __launch_bounds__(256) void gemm_bt(
    const f16* __restrict__ A, const f16* __restrict__ B,
    int M, int N, int K, int lda, int ldb,
    const float* __restrict__ bias,
    f16* __restrict__ outH, int ldo,
    float* __restrict__ stats, int sld,
    const float* __restrict__ resid, int ldr,
    float* __restrict__ outF, int ldof) {
  __shared__ f16 lA[BM * BK];
  __shared__ f16 lB[BN * BK];
  const int t = threadIdx.x;
  const int m0 = blockIdx.y * BM, n0 = blockIdx.x * BN;
  const int wave = t >> 6, lane = t & 63;
  const int wr = wave >> 1, wc = wave & 1;
  const int quad = lane >> 4, l16 = lane & 15;

  // staging: chunk = 8 rows x 128 B; lane -> (row rc, swizzled 16B slot kcs).
  // Per-lane address part is ONE 32-bit VGPR; chunk/k terms are wave-uniform
  // (readfirstlane) so they fold to SGPR adds.
  const int rc = lane >> 3;
  const int kcs = (lane & 7) ^ rc;
  const uint32_t offA = (uint32_t)(rc * lda + kcs * 8) * 2u;
  const uint32_t offB = (uint32_t)(rc * ldb + kcs * 8) * 2u;
  const char* bAp = (const char*)(A + (size_t)m0 * lda);
  const char* bBp = (const char*)(B + (size_t)n0 * ldb);
  const int wq = __builtin_amdgcn_readfirstlane(wave * 4);

  f32x4 acc[4][4];
#pragma unroll
  for (int i = 0; i < 4; i++)
#pragma unroll
    for (int j = 0; j < 4; j++)
#pragma unroll
      for (int e = 0; e < 4; e++) acc[i][j][e] = 0.0f;

  const int nk = K / BK;
  for (int kt = 0; kt < nk; ++kt) {
    const size_t kb = (size_t)(kt * BK) * 2;
#pragma unroll
    for (int j = 0; j < 4; j++) {
      const int c = wq + j;  // wave-uniform chunk id
      __builtin_amdgcn_global_load_lds(
          (const __attribute__((address_space(1))) void*)
              (bAp + ((size_t)(c * 8) * lda * 2 + kb) + offA),
          (__attribute__((address_space(3))) void*)(lA + c * 512), 16, 0, 0);
      __builtin_amdgcn_global_load_lds(
          (const __attribute__((address_space(1))) void*)
              (bBp + ((size_t)(c * 8) * ldb * 2 + kb) + offB),
          (__attribute__((address_space(3))) void*)(lB + c * 512), 16, 0, 0);
    }
    __syncthreads();

    f16x8 af[2][4], bf[2][4];
#pragma unroll
    for (int h = 0; h < 2; h++) {
      const int p = ((h * 4 + quad) ^ (l16 & 7)) * 8;
#pragma unroll
      for (int i = 0; i < 4; i++)
        af[h][i] = *(const f16x8*)(lA + (wr * 64 + i * 16 + l16) * 64 + p);
#pragma unroll
      for (int j = 0; j < 4; j++)
        bf[h][j] = *(const f16x8*)(lB + (wc * 64 + j * 16 + l16) * 64 + p);
    }
#pragma unroll
    for (int h = 0; h < 2; h++)
#pragma unroll
      for (int i = 0; i < 4; i++)
#pragma unroll
        for (int j = 0; j < 4; j++)
          acc[i][j] = __builtin_amdgcn_mfma_f32_16x16x32_f16(af[h][i], bf[h][j],
                                                             acc[i][j], 0, 0, 0);
    __syncthreads();
  }

  // ---- epilogue: one row pointer per (fi,i), imm-offset stores ----
  const int mrow = m0 + wr * 64;
  const int ncol = n0 + wc * 64;
  float bv[4];
  if constexpr (MODE == 0 || MODE == 3 || MODE == 4) {
#pragma unroll
    for (int j = 0; j < 4; j++) bv[j] = bias[ncol + j * 16 + l16];
  }
#pragma unroll
  for (int fi = 0; fi < 4; fi++) {
#pragma unroll
    for (int i = 0; i < 4; i++) {
      const int gr = mrow + fi * 16 + quad * 4 + i;
      if constexpr (MODE == 1) {
        float mx = fmaxf(fmaxf(acc[fi][0][i], acc[fi][1][i]),
                         fmaxf(acc[fi][2][i], acc[fi][3][i]));
        mx = fmaxf(mx, __shfl_xor(mx, 1));
        mx = fmaxf(mx, __shfl_xor(mx, 2));
        mx = fmaxf(mx, __shfl_xor(mx, 4));
        mx = fmaxf(mx, __shfl_xor(mx, 8));
        if (l16 == 0) stats[(size_t)gr * sld + (blockIdx.x * 2 + wc)] = mx;
        f16* rp = outH + (size_t)gr * ldo + ncol + l16;
        rp[0]  = (f16)(acc[fi][0][i] - mx);
        rp[16] = (f16)(acc[fi][1][i] - mx);
        rp[32] = (f16)(acc[fi][2][i] - mx);
        rp[48] = (f16)(acc[fi][3][i] - mx);
      } else if constexpr (MODE == 0) {
        f16* rp = outH + (size_t)gr * ldo + ncol + l16;
        rp[0]  = (f16)(acc[fi][0][i] + bv[0]);
        rp[16] = (f16)(acc[fi][1][i] + bv[1]);
        rp[32] = (f16)(acc[fi][2][i] + bv[2]);
        rp[48] = (f16)(acc[fi][3][i] + bv[3]);
      } else if constexpr (MODE == 2) {
        f16* rp = outH + (size_t)gr * ldo + ncol + l16;
        rp[0]  = (f16)acc[fi][0][i];
        rp[16] = (f16)acc[fi][1][i];
        rp[32] = (f16)acc[fi][2][i];
        rp[48] = (f16)acc[fi][3][i];
      } else if constexpr (MODE == 3) {
        float* rf = outF + (size_t)gr * ldof + ncol + l16;
        const float* rr = resid + (size_t)gr * ldr + ncol + l16;
        f16* rh = outH + (size_t)gr * ldo + ncol + l16;
        float o0 = acc[fi][0][i] + bv[0] + rr[0];
        float o1 = acc[fi][1][i] + bv[1] + rr[16];
        float o2 = acc[fi][2][i] + bv[2] + rr[32];
        float o3 = acc[fi][3][i] + bv[3] + rr[48];
        rf[0] = o0; rf[16] = o1; rf[32] = o2; rf[48] = o3;
        rh[0] = (f16)o0; rh[16] = (f16)o1; rh[32] = (f16)o2; rh[48] = (f16)o3;
      } else {  // MODE 4
        float* rf = outF + (size_t)gr * ldof + ncol + l16;
        rf[0]  = acc[fi][0][i] + bv[0];
        rf[16] = acc[fi][1][i] + bv[1];
        rf[32] = acc[fi][2][i] + bv[2];
        rf[48] = acc[fi][3][i] + bv[3];
      }
    }
  }
}

// ---------------------------------------------------------------------------
__global__ __launch_bounds__(256) void softmax_row(f16* __restrict__ S,
                                                   const float* __restrict__ stats,
                                                   int N, int sld) {
  const int row = blockIdx.x;
  const int t = threadIdx.x;
  __shared__ float sm[128];
  __shared__ float red[4];
  if (t < 128) sm[t] = stats[(size_t)row * sld + t];
  __syncthreads();
  float m = -1e30f;
#pragma unroll 16
  for (int i = 0; i < 128; i++) m = fmaxf(m, sm[i]);

  f16* rp = S + (size_t)row * N + t * 32;
  const float d = sm[t >> 1] - m;
  float ev[32];
  float sum = 0.0f;
#pragma unroll
  for (int v8 = 0; v8 < 4; v8++) {
    f16x8 v = *(f16x8*)(rp + v8 * 8);
#pragma unroll
    for (int e = 0; e < 8; e++) {
      float x = (float)v[e] + d;
      float ex = __expf(x);
      ev[v8 * 8 + e] = ex;
      sum += ex;
    }
  }
#pragma unroll
  for (int off = 32; off > 0; off >>= 1) sum += __shfl_down(sum, off);
  if ((t & 63) == 0) red[t >> 6] = sum;
  __syncthreads();
  const float rl = 1.0f / (red[0] + red[1] + red[2] + red[3]);
#pragma unroll
  for (int v8 = 0; v8 < 4; v8++) {
    f16x8 v;
#pragma unroll
    for (int e = 0; e < 8; e++) v[e] = (f16)(ev[v8 * 8 + e] * rl);
    *(f16x8*)(rp + v8 * 8) = v;
  }
}

// ---------------------------------------------------------------------------
extern "C" void kernel_launch(void* const* d_in, const int* in_sizes, int n_in,
                              void* d_out, int out_size, void* d_ws, size_t ws_size,
                              hipStream_t stream) {
  const float* O0   = (const float*)d_in[0];
  const float* Ww   = (const float*)d_in[1];
  const float* Wb   = (const float*)d_in[2];
  const float* Uw   = (const float*)d_in[3];
  const float* Ub   = (const float*)d_in[4];
  const float* Hw   = (const float*)d_in[5];
  const float* Hb   = (const float*)d_in[6];
  const float* fc0w = (const float*)d_in[7];
  const float* fc0b = (const float*)d_in[8];
  const float* fc1w = (const float*)d_in[9];
  const float* fc1b = (const float*)d_in[10];

  const int N = 8192, D = 2048, DH = 1024, DO = 1024;
  const int NQKV = 3 * DH;  // 3072

  // workspace (~168 MB)
  char* w = (char*)d_ws;
  f16* Wwh   = (f16*)w; w += (size_t)DH * D * 2;   // contiguous W|U|H = B of merged QKV
  f16* Uwh   = (f16*)w; w += (size_t)DH * D * 2;
  f16* Hwh   = (f16*)w; w += (size_t)DH * D * 2;
  f16* fc0wh = (f16*)w; w += (size_t)D * DH * 2;
  f16* fc1wh = (f16*)w; w += (size_t)DO * D * 2;
  f16* ctxh  = (f16*)w; w += (size_t)N * DH * 2;
  float* stats = (float*)w; w += (size_t)N * 128 * 4;
  float* biasC = (float*)w; w += (size_t)NQKV * 4;
  w = (char*)(((uintptr_t)w + 255) & ~(uintptr_t)255);
  f16* Sb    = (f16*)w;                  // 128 MiB: S -> P~ -> (dead) -> O1h

  // d_out scratch (96 MB): qkv [N][3072] (48) + O0h (32) + vT (16).
  // fc0 writes O1 fp32 over [0,64MB) — qkv+O0h dead; fc1 writes O2 over
  // [64,96MB) — vT dead.
  f16* oh   = (f16*)d_out;
  f16* qkv  = oh;                                   // q|k|v interleaved, ld 3072
  f16* qh   = qkv;
  f16* kh   = qkv + DH;
  f16* vh   = qkv + 2 * DH;
  f16* O0h  = oh + (size_t)N * NQKV;
  f16* vT   = O0h + (size_t)N * D;
  f16* O1h  = Sb;                                   // after ctx, Sb dead

  // 1) fp32 -> fp16 conversions + bias concat
  {
    int n = DH * D;
    int grid = n / 1024;
    cvt_f32_f16<<<grid, 256, 0, stream>>>(Ww, Wwh, n);
    cvt_f32_f16<<<grid, 256, 0, stream>>>(Uw, Uwh, n);
    cvt_f32_f16<<<grid, 256, 0, stream>>>(Hw, Hwh, n);
    cvt_f32_f16<<<grid, 256, 0, stream>>>(fc0w, fc0wh, n);
    cvt_f32_f16<<<grid, 256, 0, stream>>>(fc1w, fc1wh, n);
    cvt_f32_f16<<<(N * D) / 1024, 256, 0, stream>>>(O0, O0h, N * D);
    hipMemcpyAsync(biasC,          Wb, DH * 4, hipMemcpyDeviceToDevice, stream);
    hipMemcpyAsync(biasC + DH,     Ub, DH * 4, hipMemcpyDeviceToDevice, stream);
    hipMemcpyAsync(biasC + 2 * DH, Hb, DH * 4, hipMemcpyDeviceToDevice, stream);
  }

  // 2) merged QKV: [N][3072] = O0h @ [Ww;Uw;Hw]^T + biasC
  gemm_bt<0><<<dim3(NQKV / BN, N / BM), 256, 0, stream>>>(
      O0h, Wwh, N, NQKV, D, D, D, biasC,
      qkv, NQKV, nullptr, 0, nullptr, 0, nullptr, 0);

  // 3) v -> vT
  transpose_f16<<<dim3(DH / 64, N / 64), 256, 0, stream>>>(vh, NQKV, vT, N, DH);

  // 4) S = q k^T (stored as s - tilemax) + per-64-col-tile row maxes
  gemm_bt<1><<<dim3(N / BN, N / BM), 256, 0, stream>>>(
      qh, kh, N, N, DH, NQKV, NQKV, nullptr, Sb, N, stats, 128,
      nullptr, 0, nullptr, 0);

  // 5) softmax in place (folds 1/l)
  softmax_row<<<N, 256, 0, stream>>>(Sb, stats, N, 128);

  // 6) ctx = P~ @ v
  gemm_bt<2><<<dim3(DH / BN, N / BM), 256, 0, stream>>>(
      Sb, vT, N, DH, N, N, N, nullptr, ctxh, DH, nullptr, 0, nullptr, 0,
      nullptr, 0);

  // 7) O1 = O0 + ctx @ fc0w^T + fc0b -> fp32 d_out + fp16 O1h
  gemm_bt<3><<<dim3(D / BN, N / BM), 256, 0, stream>>>(
      ctxh, fc0wh, N, D, DH, DH, DH, fc0b, O1h, D, nullptr, 0,
      O0, D, (float*)d_out, D);

  // 8) O2 = O1 @ fc1w^T + fc1b
  gemm_bt<4><<<dim3(DO / BN, N / BM), 256, 0, stream>>>(
      O1h, fc1wh, N, DO, D, D, D, fc1b, nullptr, 0, nullptr, 0,
      nullptr, 0, (float*)d_out + (size_t)N * D, DO);
}

// Round 4
// 855.591 us; speedup vs baseline: 1.2898x; 1.0086x over previous
//
#include <hip/hip_runtime.h>
#include <cstdint>
#include <cstddef>

typedef _Float16 f16;
typedef _Float16 f16x8 __attribute__((ext_vector_type(8)));
typedef _Float16 f16x4 __attribute__((ext_vector_type(4)));
typedef float    f32x4 __attribute__((ext_vector_type(4)));

#define BM 128
#define BN 128
#define BK 64
// LDS tile: 128 rows x 64 halfs, no pad (global_load_lds needs lane-contiguous
// dest). 16B slot p of row r holds global k-chunk (p ^ (r&7)); fragment
// ds_read_b128 lands 2-way per bank (free). Verified R2/R3: 0 conflicts.

// ---------------------------------------------------------------------------
__global__ __launch_bounds__(256) void cvt_f32_f16(const float* __restrict__ in,
                                                   f16* __restrict__ out, int n) {
  int i = (blockIdx.x * 256 + threadIdx.x) * 4;
  if (i < n) {
    float4 v = *(const float4*)(in + i);
    f16x4 h; h[0] = (f16)v.x; h[1] = (f16)v.y; h[2] = (f16)v.z; h[3] = (f16)v.w;
    *(f16x4*)(out + i) = h;
  }
}

// ---------------------------------------------------------------------------
// in [R][ldi] (C-col slice) -> out [C][R]
__global__ __launch_bounds__(256) void transpose_f16(const f16* __restrict__ in,
                                                     int ldi,
                                                     f16* __restrict__ out,
                                                     int R, int C) {
  __shared__ f16 tile[64][65];
  const int r0 = blockIdx.y * 64, c0 = blockIdx.x * 64;
  const int t = threadIdx.x;
#pragma unroll
  for (int p = 0; p < 2; p++) {
    int s = t + p * 256;
    int r = s >> 3, q = s & 7;
    f16x8 v = *(const f16x8*)(in + (size_t)(r0 + r) * ldi + c0 + q * 8);
#pragma unroll
    for (int e = 0; e < 8; e++) tile[r][q * 8 + e] = v[e];
  }
  __syncthreads();
#pragma unroll
  for (int p = 0; p < 2; p++) {
    int s = t + p * 256;
    int r = s >> 3, q = s & 7;
    f16x8 v;
#pragma unroll
    for (int e = 0; e < 8; e++) v[e] = tile[q * 8 + e][r];
    *(f16x8*)(out + (size_t)(c0 + r) * R + r0 + q * 8) = v;
  }
}

// ---------------------------------------------------------------------------
// BT GEMM, fp16: C[m][n] = sum_k A[m][k]*B[n][k]
// MODE 0: outH = acc + bias[n]                                  (QKV merged)
// MODE 1: outH = exp(acc - tile_rowmax); statsM/statsS = per-(row,64tile)
//         max / sum-of-exp                                      (S)
// MODE 2: A fragments scaled by alphaT[kt][row]; outH = acc     (ctx)
// MODE 3: outF = acc + bias + resid (f32); outH = same (f16)    (fc0)
// MODE 4: outF = acc + bias (f32)                               (fc1)
// ---------------------------------------------------------------------------
template <int MODE>
__global__ __launch_bounds__(256) void gemm_bt(
    const f16* __restrict__ A, const f16* __restrict__ B,
    int M, int N, int K, int lda, int ldb,
    const float* __restrict__ bias,
    f16* __restrict__ outH, int ldo,
    float* __restrict__ statsM, float* __restrict__ statsS, int sld,
    const float* __restrict__ alphaT,
    const float* __restrict__ resid, int ldr,
    float* __restrict__ outF, int ldof) {
  __shared__ f16 lA[BM * BK];
  __shared__ f16 lB[BN * BK];
  const int t = threadIdx.x;
  const int m0 = blockIdx.y * BM, n0 = blockIdx.x * BN;
  const int wave = t >> 6, lane = t & 63;
  const int wr = wave >> 1, wc = wave & 1;
  const int quad = lane >> 4, l16 = lane & 15;

  const int rc = lane >> 3;
  const int kcs = (lane & 7) ^ rc;
  const uint32_t offA = (uint32_t)(rc * lda + kcs * 8) * 2u;
  const uint32_t offB = (uint32_t)(rc * ldb + kcs * 8) * 2u;
  const char* bAp = (const char*)(A + (size_t)m0 * lda);
  const char* bBp = (const char*)(B + (size_t)n0 * ldb);
  const int wq = __builtin_amdgcn_readfirstlane(wave * 4);

  f32x4 acc[4][4];
#pragma unroll
  for (int i = 0; i < 4; i++)
#pragma unroll
    for (int j = 0; j < 4; j++)
#pragma unroll
      for (int e = 0; e < 4; e++) acc[i][j][e] = 0.0f;

  const int nk = K / BK;
  for (int kt = 0; kt < nk; ++kt) {
    // MODE 2: prefetch per-row alpha for this 64-wide K tile (tile id == kt).
    float al[4];
    if constexpr (MODE == 2) {
      const float* ap = alphaT + (size_t)kt * M + m0 + wr * 64 + l16;
      al[0] = ap[0]; al[1] = ap[16]; al[2] = ap[32]; al[3] = ap[48];
    }
    const size_t kb = (size_t)(kt * BK) * 2;
#pragma unroll
    for (int j = 0; j < 4; j++) {
      const int c = wq + j;  // wave-uniform chunk id
      __builtin_amdgcn_global_load_lds(
          (const __attribute__((address_space(1))) void*)
              (bAp + ((size_t)(c * 8) * lda * 2 + kb) + offA),
          (__attribute__((address_space(3))) void*)(lA + c * 512), 16, 0, 0);
      __builtin_amdgcn_global_load_lds(
          (const __attribute__((address_space(1))) void*)
              (bBp + ((size_t)(c * 8) * ldb * 2 + kb) + offB),
          (__attribute__((address_space(3))) void*)(lB + c * 512), 16, 0, 0);
    }
    __syncthreads();

    f16x8 af[2][4], bf[2][4];
#pragma unroll
    for (int h = 0; h < 2; h++) {
      const int p = ((h * 4 + quad) ^ (l16 & 7)) * 8;
#pragma unroll
      for (int i = 0; i < 4; i++)
        af[h][i] = *(const f16x8*)(lA + (wr * 64 + i * 16 + l16) * 64 + p);
#pragma unroll
      for (int j = 0; j < 4; j++)
        bf[h][j] = *(const f16x8*)(lB + (wc * 64 + j * 16 + l16) * 64 + p);
    }
    if constexpr (MODE == 2) {
#pragma unroll
      for (int i = 0; i < 4; i++) {
        const f16 ah = (f16)al[i];
        af[0][i] = af[0][i] * ah;
        af[1][i] = af[1][i] * ah;
      }
    }
#pragma unroll
    for (int h = 0; h < 2; h++)
#pragma unroll
      for (int i = 0; i < 4; i++)
#pragma unroll
        for (int j = 0; j < 4; j++)
          acc[i][j] = __builtin_amdgcn_mfma_f32_16x16x32_f16(af[h][i], bf[h][j],
                                                             acc[i][j], 0, 0, 0);
    __syncthreads();
  }

  // ---- epilogue ----
  const int mrow = m0 + wr * 64;
  const int ncol = n0 + wc * 64;
  float bv[4];
  if constexpr (MODE == 0 || MODE == 3 || MODE == 4) {
#pragma unroll
    for (int j = 0; j < 4; j++) bv[j] = bias[ncol + j * 16 + l16];
  }
#pragma unroll
  for (int fi = 0; fi < 4; fi++) {
#pragma unroll
    for (int i = 0; i < 4; i++) {
      const int gr = mrow + fi * 16 + quad * 4 + i;
      if constexpr (MODE == 1) {
        float mx = fmaxf(fmaxf(acc[fi][0][i], acc[fi][1][i]),
                         fmaxf(acc[fi][2][i], acc[fi][3][i]));
        mx = fmaxf(mx, __shfl_xor(mx, 1));
        mx = fmaxf(mx, __shfl_xor(mx, 2));
        mx = fmaxf(mx, __shfl_xor(mx, 4));
        mx = fmaxf(mx, __shfl_xor(mx, 8));
        float e0 = __expf(acc[fi][0][i] - mx);
        float e1 = __expf(acc[fi][1][i] - mx);
        float e2 = __expf(acc[fi][2][i] - mx);
        float e3 = __expf(acc[fi][3][i] - mx);
        float sm = (e0 + e1) + (e2 + e3);
        sm += __shfl_xor(sm, 1);
        sm += __shfl_xor(sm, 2);
        sm += __shfl_xor(sm, 4);
        sm += __shfl_xor(sm, 8);
        if (l16 == 0) {
          statsM[(size_t)gr * sld + (blockIdx.x * 2 + wc)] = mx;
          statsS[(size_t)gr * sld + (blockIdx.x * 2 + wc)] = sm;
        }
        f16* rp = outH + (size_t)gr * ldo + ncol + l16;
        rp[0]  = (f16)e0;
        rp[16] = (f16)e1;
        rp[32] = (f16)e2;
        rp[48] = (f16)e3;
      } else if constexpr (MODE == 0) {
        f16* rp = outH + (size_t)gr * ldo + ncol + l16;
        rp[0]  = (f16)(acc[fi][0][i] + bv[0]);
        rp[16] = (f16)(acc[fi][1][i] + bv[1]);
        rp[32] = (f16)(acc[fi][2][i] + bv[2]);
        rp[48] = (f16)(acc[fi][3][i] + bv[3]);
      } else if constexpr (MODE == 2) {
        f16* rp = outH + (size_t)gr * ldo + ncol + l16;
        rp[0]  = (f16)acc[fi][0][i];
        rp[16] = (f16)acc[fi][1][i];
        rp[32] = (f16)acc[fi][2][i];
        rp[48] = (f16)acc[fi][3][i];
      } else if constexpr (MODE == 3) {
        float* rf = outF + (size_t)gr * ldof + ncol + l16;
        const float* rr = resid + (size_t)gr * ldr + ncol + l16;
        f16* rh = outH + (size_t)gr * ldo + ncol + l16;
        float o0 = acc[fi][0][i] + bv[0] + rr[0];
        float o1 = acc[fi][1][i] + bv[1] + rr[16];
        float o2 = acc[fi][2][i] + bv[2] + rr[32];
        float o3 = acc[fi][3][i] + bv[3] + rr[48];
        rf[0] = o0; rf[16] = o1; rf[32] = o2; rf[48] = o3;
        rh[0] = (f16)o0; rh[16] = (f16)o1; rh[32] = (f16)o2; rh[48] = (f16)o3;
      } else {  // MODE 4
        float* rf = outF + (size_t)gr * ldof + ncol + l16;
        rf[0]  = acc[fi][0][i] + bv[0];
        rf[16] = acc[fi][1][i] + bv[1];
        rf[32] = acc[fi][2][i] + bv[2];
        rf[48] = acc[fi][3][i] + bv[3];
      }
    }
  }
}

// ---------------------------------------------------------------------------
// Per-row softmax factors from per-tile (max, sum):
//   m = max_t m_t;  l = sum_t exp(m_t - m) * s_t;  alphaT[t][row] = exp(m_t-m)/l
// Block = 64 rows x 128 tiles; 4 threads per row (32 tiles each).
// ---------------------------------------------------------------------------
__global__ __launch_bounds__(256) void alpha_from_stats(
    const float* __restrict__ sM, const float* __restrict__ sS,
    float* __restrict__ aT, int rows) {
  __shared__ float alph[128][65];
  const int t = threadIdx.x;
  const int r = t >> 2, j = t & 3;
  const int row = blockIdx.x * 64 + r;
  const float* pm = sM + (size_t)row * 128 + j * 32;
  const float* ps = sS + (size_t)row * 128 + j * 32;
  float mv[32];
  float mx = -1e30f;
#pragma unroll
  for (int c = 0; c < 32; c++) { mv[c] = pm[c]; mx = fmaxf(mx, mv[c]); }
  mx = fmaxf(mx, __shfl_xor(mx, 1));
  mx = fmaxf(mx, __shfl_xor(mx, 2));
  float ev[32];
  float sum = 0.0f;
#pragma unroll
  for (int c = 0; c < 32; c++) {
    ev[c] = __expf(mv[c] - mx);
    sum += ev[c] * ps[c];
  }
  sum += __shfl_xor(sum, 1);
  sum += __shfl_xor(sum, 2);
  const float rl = 1.0f / sum;
#pragma unroll
  for (int c = 0; c < 32; c++) alph[j * 32 + c][r] = ev[c] * rl;
  __syncthreads();
  const int wid = t >> 6, rr = t & 63;
#pragma unroll
  for (int c = 0; c < 32; c++) {
    const int tg = c * 4 + wid;
    aT[(size_t)tg * rows + blockIdx.x * 64 + rr] = alph[tg][rr];
  }
}

// ---------------------------------------------------------------------------
extern "C" void kernel_launch(void* const* d_in, const int* in_sizes, int n_in,
                              void* d_out, int out_size, void* d_ws, size_t ws_size,
                              hipStream_t stream) {
  const float* O0   = (const float*)d_in[0];
  const float* Ww   = (const float*)d_in[1];
  const float* Wb   = (const float*)d_in[2];
  const float* Uw   = (const float*)d_in[3];
  const float* Ub   = (const float*)d_in[4];
  const float* Hw   = (const float*)d_in[5];
  const float* Hb   = (const float*)d_in[6];
  const float* fc0w = (const float*)d_in[7];
  const float* fc0b = (const float*)d_in[8];
  const float* fc1w = (const float*)d_in[9];
  const float* fc1b = (const float*)d_in[10];

  const int N = 8192, D = 2048, DH = 1024, DO = 1024;
  const int NQKV = 3 * DH;

  // workspace (~168 MB, same footprint as R3)
  char* w = (char*)d_ws;
  f16* Wwh   = (f16*)w; w += (size_t)DH * D * 2;   // W|U|H contiguous = merged B
  f16* Uwh   = (f16*)w; w += (size_t)DH * D * 2;
  f16* Hwh   = (f16*)w; w += (size_t)DH * D * 2;
  f16* fc0wh = (f16*)w; w += (size_t)D * DH * 2;
  f16* fc1wh = (f16*)w; w += (size_t)DO * D * 2;
  float* aT  = (float*)w; w += (size_t)128 * N * 4;          // 4 MB, alive thru ctx
  // union: statsM/statsS (S-GEMM + alpha) then ctxh (ctx onward; stats dead)
  char* un = w; w += (size_t)N * DH * 2;                     // 16 MB
  float* statsM = (float*)un;
  float* statsS = statsM + (size_t)N * 128;
  f16* ctxh = (f16*)un;
  float* biasC = (float*)w; w += (size_t)NQKV * 4;
  w = (char*)(((uintptr_t)w + 255) & ~(uintptr_t)255);
  f16* Sb = (f16*)w;                    // 128 MiB: S(exp'd) -> dead -> O1h

  // d_out scratch (96 MB): qkv [N][3072] + O0h [N][D] + vT [DH][N]
  // fc0 writes O1 fp32 over [0,64MB) (qkv+half of O0h dead); fc1 writes O2
  // over [64,96MB) (vT dead by then).
  f16* oh   = (f16*)d_out;
  f16* qkv  = oh;
  f16* qh   = qkv;
  f16* kh   = qkv + DH;
  f16* vh   = qkv + 2 * DH;
  f16* O0h  = oh + (size_t)N * NQKV;
  f16* vT   = O0h + (size_t)N * D;
  f16* O1h  = Sb;

  // 1) fp32 -> fp16 conversions + bias concat
  {
    int n = DH * D;
    int grid = n / 1024;
    cvt_f32_f16<<<grid, 256, 0, stream>>>(Ww, Wwh, n);
    cvt_f32_f16<<<grid, 256, 0, stream>>>(Uw, Uwh, n);
    cvt_f32_f16<<<grid, 256, 0, stream>>>(Hw, Hwh, n);
    cvt_f32_f16<<<grid, 256, 0, stream>>>(fc0w, fc0wh, n);
    cvt_f32_f16<<<grid, 256, 0, stream>>>(fc1w, fc1wh, n);
    cvt_f32_f16<<<(N * D) / 1024, 256, 0, stream>>>(O0, O0h, N * D);
    hipMemcpyAsync(biasC,          Wb, DH * 4, hipMemcpyDeviceToDevice, stream);
    hipMemcpyAsync(biasC + DH,     Ub, DH * 4, hipMemcpyDeviceToDevice, stream);
    hipMemcpyAsync(biasC + 2 * DH, Hb, DH * 4, hipMemcpyDeviceToDevice, stream);
  }

  // 2) merged QKV: [N][3072] = O0h @ [Ww;Uw;Hw]^T + biasC
  gemm_bt<0><<<dim3(NQKV / BN, N / BM), 256, 0, stream>>>(
      O0h, Wwh, N, NQKV, D, D, D, biasC,
      qkv, NQKV, nullptr, nullptr, 0, nullptr, nullptr, 0, nullptr, 0);

  // 3) v -> vT
  transpose_f16<<<dim3(DH / 64, N / 64), 256, 0, stream>>>(vh, NQKV, vT, N, DH);

  // 4) S tiles: store exp(s - tile_max) + per-tile (max, sum)
  gemm_bt<1><<<dim3(N / BN, N / BM), 256, 0, stream>>>(
      qh, kh, N, N, DH, NQKV, NQKV, nullptr, Sb, N,
      statsM, statsS, 128, nullptr, nullptr, 0, nullptr, 0);

  // 5) alpha factors (replaces full softmax pass)
  alpha_from_stats<<<N / 64, 256, 0, stream>>>(statsM, statsS, aT, N);

  // 6) ctx = softmax(S) @ v, via alpha-scaled A fragments
  gemm_bt<2><<<dim3(DH / BN, N / BM), 256, 0, stream>>>(
      Sb, vT, N, DH, N, N, N, nullptr, ctxh, DH,
      nullptr, nullptr, 0, aT, nullptr, 0, nullptr, 0);

  // 7) O1 = O0 + ctx @ fc0w^T + fc0b -> fp32 d_out + fp16 O1h
  gemm_bt<3><<<dim3(D / BN, N / BM), 256, 0, stream>>>(
      ctxh, fc0wh, N, D, DH, DH, DH, fc0b, O1h, D,
      nullptr, nullptr, 0, nullptr, O0, D, (float*)d_out, D);

  // 8) O2 = O1 @ fc1w^T + fc1b
  gemm_bt<4><<<dim3(DO / BN, N / BM), 256, 0, stream>>>(
      O1h, fc1wh, N, DO, D, D, D, fc1b, nullptr, 0,
      nullptr, nullptr, 0, nullptr, nullptr, 0,
      (float*)d_out + (size_t)N * D, DO);
}